// Round 5
// baseline (106.556 us; speedup 1.0000x reference)
//
#include <hip/hip_runtime.h>
#include <climits>
#include <math.h>

#define N_NODES 100000
#define N_EGO   8192
#define N_EDGES 1600000
#define HIDDEN  128
#define MID     64
#define OUT_D   16
#define CAP     96                       // per-ego neighbor cap; P(deg>=96) ~ 1e-44
#define BM_WORDS ((N_NODES + 31) / 32)   // 12.5KB ego bitmap, L1/L2-resident

#define EB      256                      // edge-scan blocks
#define FSLICE  (N_EDGES / EB)           // 6250 edges/slice
#define FS2     (FSLICE / 2)             // 3125 int2 per slice
#define ZBLK    ((N_NODES + 1023) / 1024)          // 98 zeroing blocks
#define P1_GRID (3 + ZBLK)                          // fold(2) + rep(1) + zero(98)

// =============================== DISPATCH 1 ==================================
// block 0      : fold F,C,G   (mid = relu(s4·F + t·G + C))
//                F[d][m] = sum_k convW[d][k] w1[k][m]; C[m] = b1[m] + sum_k convB[k] w1[k][m]
// block 1      : fold W2T     (W2T[o][m] = w2[m][o])
// block 2      : zero bitmap -> __syncthreads -> racy rep store + bitmap set
// blocks 3..   : zero deg and cnt
__global__ __launch_bounds__(1024) void k_p1(
        const int* __restrict__ ego_idx,
        const float* __restrict__ convW, const float* __restrict__ convB,
        const float* __restrict__ w1, const float* __restrict__ b1,
        const float* __restrict__ w2,
        int* __restrict__ rep, unsigned* __restrict__ bitmap,
        unsigned* __restrict__ cnt, unsigned* __restrict__ deg,
        float* __restrict__ F, float* __restrict__ G, float* __restrict__ C,
        float* __restrict__ W2T) {
    __shared__ float fp[640];
    const int bid = blockIdx.x, tid = threadIdx.x;

    if (bid == 0) {
        // rows 0..3 = convW -> F; row 4 = convB -> C. 2 threads/output, 64-FMA halves.
        if (tid < 640) {
            const int outi = tid >> 1, q = tid & 1;
            const int row = outi >> 6, m = outi & 63;
            const float* src = (row < 4) ? (convW + row * HIDDEN) : convB;
            float s = 0.f;
            const int k0 = q * 64;
            #pragma unroll 8
            for (int k = k0; k < k0 + 64; ++k)
                s = fmaf(src[k], w1[k * MID + m], s);
            fp[tid] = s;
        }
        __syncthreads();
        if (tid < 320) {
            const int row = tid >> 6, m = tid & 63;
            const float v = fp[2 * tid] + fp[2 * tid + 1];
            if (row < 4) F[row * MID + m] = v;
            else         C[m] = v + b1[m];
        }
        if (tid < MID) G[tid] = w1[HIDDEN * MID + tid];
    } else if (bid == 1) {
        const int o = tid >> 6, m = tid & 63;          // 1024 = 16*64 exactly
        W2T[tid] = w2[m * OUT_D + o];
    } else if (bid == 2) {
        for (int i = tid; i < BM_WORDS; i += 1024) bitmap[i] = 0u;
        __syncthreads();                               // in-block ordering only
        for (int i = tid; i < N_EGO; i += 1024) {
            const int node = ego_idx[i];
            rep[node] = i;                             // racy; any single winner is consistent
            atomicOr(&bitmap[node >> 5], 1u << (node & 31));
        }
    } else {
        const int i = (bid - 3) * 1024 + tid;          // 98 blocks cover 100,352
        if (i < N_NODES) deg[i] = 0u;
        if (i < N_EGO)   cnt[i] = 0u;
    }
}

// =============================== DISPATCH 2 ==================================
// Single edge pass: global u32 atomicAdd degree + bitmap-filtered ego lists.
// 1.6M atomics over 100K L2-resident counters (~16/addr, low contention).
__global__ __launch_bounds__(1024) void k_p2(
        const int* __restrict__ srcp, const int* __restrict__ dstp,
        const unsigned* __restrict__ bitmap, const int* __restrict__ rep,
        unsigned* __restrict__ cnt, unsigned* __restrict__ deg,
        int* __restrict__ list) {
    const int bid = blockIdx.x, tid = threadIdx.x;
    const int2* dp = reinterpret_cast<const int2*>(dstp + bid * FSLICE);
    const int2* sp = reinterpret_cast<const int2*>(srcp + bid * FSLICE);
    for (int i = tid; i < FS2; i += 1024) {
        const int2 d = dp[i];
        const int2 s = sp[i];
        const int dv[2] = {d.x, d.y};
        const int sv[2] = {s.x, s.y};
        #pragma unroll
        for (int k = 0; k < 2; ++k) {
            const unsigned aa = (unsigned)dv[k];               // in [0, N_NODES)
            atomicAdd(&deg[aa], 1u);
            if ((bitmap[aa >> 5] >> (aa & 31)) & 1u) {         // ~8% pass
                const int rr = rep[dv[k]];
                const unsigned pos = atomicAdd(&cnt[rr], 1u);
                if (pos < CAP) list[rr * CAP + pos] = sv[k];
            }
        }
    }
}

// =============================== DISPATCH 3 ==================================
// 256 blocks x 512 threads: 8 waves x 4 egos = 32 egos/block.
// 16 lanes/ego: gather sum (dinv = rsqrtf(deg+1) on read) -> shuffle reduce
// -> folded MLP -> sigmoid.
__global__ __launch_bounds__(512) void k_p3(
    const float* __restrict__ data1, const float* __restrict__ ego_time,
    const int* __restrict__ ego_idx,
    const float* __restrict__ F, const float* __restrict__ G,
    const float* __restrict__ C, const float* __restrict__ W2T,
    const float* __restrict__ b2,
    const int* __restrict__ rep, const unsigned* __restrict__ cnt,
    const int* __restrict__ list, const unsigned* __restrict__ deg,
    float* __restrict__ out) {
    __shared__ float mid_s[32 * MID];                  // 8KB
    const int tid = threadIdx.x, bid = blockIdx.x;
    const int wv = tid >> 6, lane = tid & 63;
    const int e = lane >> 4, sl = lane & 15;
    const int eg = wv * 4 + e;
    const int i  = bid * 32 + eg;                      // 256*32 = 8192
    const int node = ego_idx[i];
    const int r    = rep[node];
    int n = (int)cnt[r]; if (n > CAP) n = CAP;
    const float dvd = rsqrtf((float)(deg[node] + 1u)); // +1 self-loop
    const int* lrow = list + (size_t)r * CAP;

    float px = 0.f, py = 0.f, pz = 0.f, pw = 0.f;
    for (int k = sl; k < n; k += 16) {
        const int s = lrow[k];
        const float wn = rsqrtf((float)(deg[s] + 1u));
        const float4 x = reinterpret_cast<const float4*>(data1)[s];
        px = fmaf(wn, x.x, px); py = fmaf(wn, x.y, py);
        pz = fmaf(wn, x.z, pz); pw = fmaf(wn, x.w, pw);
    }
    if (sl == 15) {                                    // self-loop term
        const float4 x = reinterpret_cast<const float4*>(data1)[node];
        px = fmaf(dvd, x.x, px); py = fmaf(dvd, x.y, py);
        pz = fmaf(dvd, x.z, pz); pw = fmaf(dvd, x.w, pw);
    }
    #pragma unroll
    for (int m = 1; m <= 8; m <<= 1) {
        px += __shfl_xor(px, m); py += __shfl_xor(py, m);
        pz += __shfl_xor(pz, m); pw += __shfl_xor(pw, m);
    }
    const float sx = dvd * px, sy = dvd * py, sz = dvd * pz, sw = dvd * pw;
    const float t  = ego_time[i];

    const float4 f0 = reinterpret_cast<const float4*>(F)[0 * 16 + sl];
    const float4 f1 = reinterpret_cast<const float4*>(F)[1 * 16 + sl];
    const float4 f2 = reinterpret_cast<const float4*>(F)[2 * 16 + sl];
    const float4 f3 = reinterpret_cast<const float4*>(F)[3 * 16 + sl];
    const float4 g  = reinterpret_cast<const float4*>(G)[sl];
    const float4 c  = reinterpret_cast<const float4*>(C)[sl];
    float4 mid;
    mid.x = fmaxf(fmaf(sx, f0.x, fmaf(sy, f1.x, fmaf(sz, f2.x, fmaf(sw, f3.x, fmaf(t, g.x, c.x))))), 0.f);
    mid.y = fmaxf(fmaf(sx, f0.y, fmaf(sy, f1.y, fmaf(sz, f2.y, fmaf(sw, f3.y, fmaf(t, g.y, c.y))))), 0.f);
    mid.z = fmaxf(fmaf(sx, f0.z, fmaf(sy, f1.z, fmaf(sz, f2.z, fmaf(sw, f3.z, fmaf(t, g.z, c.z))))), 0.f);
    mid.w = fmaxf(fmaf(sx, f0.w, fmaf(sy, f1.w, fmaf(sz, f2.w, fmaf(sw, f3.w, fmaf(t, g.w, c.w))))), 0.f);
    reinterpret_cast<float4*>(mid_s + eg * MID)[sl] = mid;
    __syncthreads();

    float acc = b2[sl];
    const float4* m4 = reinterpret_cast<const float4*>(mid_s + eg * MID);
    const float4* w4 = reinterpret_cast<const float4*>(W2T + sl * MID);
    #pragma unroll
    for (int q = 0; q < 16; ++q) {
        const float4 mm = m4[q]; const float4 ww = w4[q];
        acc = fmaf(mm.x, ww.x, acc); acc = fmaf(mm.y, ww.y, acc);
        acc = fmaf(mm.z, ww.z, acc); acc = fmaf(mm.w, ww.w, acc);
    }
    out[(size_t)i * OUT_D + sl] = 1.0f / (1.0f + expf(-acc));
}

// ============================== launcher =====================================

extern "C" void kernel_launch(void* const* d_in, const int* in_sizes, int n_in,
                              void* d_out, int out_size, void* d_ws, size_t ws_size,
                              hipStream_t stream) {
    const float* data1    = (const float*)d_in[0];
    const int*   edge     = (const int*)d_in[1];   // [2, N_EDGES] int32
    const float* ego_time = (const float*)d_in[2];
    const int*   ego_idx  = (const int*)d_in[3];
    const float* convW    = (const float*)d_in[4];
    const float* convB    = (const float*)d_in[5];
    const float* w1       = (const float*)d_in[6];
    const float* b1       = (const float*)d_in[7];
    const float* w2       = (const float*)d_in[8];
    const float* b2       = (const float*)d_in[9];
    float* out = (float*)d_out;

    char* ws = (char*)d_ws;
    size_t off = 0;
    auto alloc = [&](size_t b) { size_t p = off; off += (b + 511) & ~(size_t)511; return p; };
    int*      rep    = (int*)     (ws + alloc((size_t)N_NODES * 4));
    unsigned* bitmap = (unsigned*)(ws + alloc((size_t)BM_WORDS * 4));
    unsigned* cnt    = (unsigned*)(ws + alloc((size_t)N_EGO * 4));
    unsigned* deg    = (unsigned*)(ws + alloc((size_t)N_NODES * 4));
    float*    F      = (float*)   (ws + alloc((size_t)4 * MID * 4));
    float*    G      = (float*)   (ws + alloc((size_t)MID * 4));
    float*    C      = (float*)   (ws + alloc((size_t)MID * 4));
    float*    W2T    = (float*)   (ws + alloc((size_t)OUT_D * MID * 4));
    int*      list   = (int*)     (ws + alloc((size_t)N_EGO * CAP * 4));
    const size_t need = off + 512;                  // ~4.1 MB total

    const int* srcp = edge;
    const int* dstp = edge + N_EDGES;

    if (ws_size < need) return;                     // cannot run (ws far larger in practice)

    hipLaunchKernelGGL(k_p1, dim3(P1_GRID), dim3(1024), 0, stream,
                       ego_idx, convW, convB, w1, b1, w2,
                       rep, bitmap, cnt, deg, F, G, C, W2T);
    hipLaunchKernelGGL(k_p2, dim3(EB), dim3(1024), 0, stream,
                       srcp, dstp, bitmap, rep, cnt, deg, list);
    hipLaunchKernelGGL(k_p3, dim3(N_EGO / 32), dim3(512), 0, stream,
                       data1, ego_time, ego_idx, F, G, C, W2T, b2,
                       rep, cnt, list, deg, out);
}

// Round 6
// 47.053 us; speedup vs baseline: 2.2646x; 2.2646x over previous
//
#include <hip/hip_runtime.h>
#include <climits>
#include <math.h>

#define N_NODES 100000
#define N_EGO   8192
#define N_EDGES 1600000
#define HIDDEN  128
#define MID     64
#define OUT_D   16
#define CAP     96                       // per-ego neighbor cap; P(deg>=96) ~ 1e-44
#define BM_WORDS ((N_NODES + 31) / 32)   // 12.5KB ego bitmap, L1-resident
#define NR      2                        // node ranges (u8 LDS histogram)
#define RSZ     50000                    // nodes per range
#define RWORDS  (RSZ / 4)                // 12500 u32 words = 50KB LDS
#define BPR     128                      // blocks (edge slices) per range
#define SLICE   (N_EDGES / BPR)          // 12500 edges per block
#define S4TOT   (SLICE / 4)              // 3125 int4s per slice
#define EPW     4                        // egos per wave in k_mlp

// =============================== DISPATCH 1 ==================================
// block 0 : fold F,C,G  (mid = relu(s4·F + t·G + C))
//           F[d][m] = sum_k convW[d][k] w1[k][m]; C[m] = b1[m] + sum_k convB[k] w1[k][m]
// block 1 : fold W2T    (W2T[o][m] = w2[m][o])
// block 2 : zero bitmap + cnt    (rep needs NO init: racy-store winner, proven r4/r5)
__global__ __launch_bounds__(1024) void k_init3(
        const float* __restrict__ convW, const float* __restrict__ convB,
        const float* __restrict__ w1, const float* __restrict__ b1,
        const float* __restrict__ w2,
        unsigned* __restrict__ bitmap, unsigned* __restrict__ cnt,
        float* __restrict__ F, float* __restrict__ G, float* __restrict__ C,
        float* __restrict__ W2T) {
    __shared__ float fp[640];
    const int bid = blockIdx.x, tid = threadIdx.x;
    if (bid == 0) {
        // rows 0..3 = convW -> F; row 4 = convB -> C. 2 threads/output, 64-FMA halves.
        if (tid < 640) {
            const int outi = tid >> 1, q = tid & 1;
            const int row = outi >> 6, m = outi & 63;
            const float* src = (row < 4) ? (convW + row * HIDDEN) : convB;
            float s = 0.f;
            const int k0 = q * 64;
            #pragma unroll 8
            for (int k = k0; k < k0 + 64; ++k)
                s = fmaf(src[k], w1[k * MID + m], s);
            fp[tid] = s;
        }
        __syncthreads();
        if (tid < 320) {
            const int row = tid >> 6, m = tid & 63;
            const float v = fp[2 * tid] + fp[2 * tid + 1];
            if (row < 4) F[row * MID + m] = v;
            else         C[m] = v + b1[m];
        }
        if (tid < MID) G[tid] = w1[HIDDEN * MID + tid];
    } else if (bid == 1) {
        const int o = tid >> 6, m = tid & 63;          // 1024 = 16*64 exactly
        W2T[tid] = w2[m * OUT_D + o];
    } else {
        for (int i = tid; i < BM_WORDS; i += 1024) bitmap[i] = 0u;
        for (int i = tid; i < N_EGO; i += 1024)    cnt[i] = 0u;
    }
}

// =============================== DISPATCH 2 ==================================
__global__ void k_rep(const int* __restrict__ ego_idx, int* __restrict__ rep,
                      unsigned* __restrict__ bitmap) {
    int i = blockIdx.x * blockDim.x + threadIdx.x;
    if (i < N_EGO) {
        int node = ego_idx[i];
        rep[node] = i;                                 // racy; any single winner is consistent
        atomicOr(&bitmap[node >> 5], 1u << (node & 31));
    }
}

// =============================== DISPATCH 3 ==================================
// 256 blocks (2 ranges x 128 slices): u8-packed LDS histogram + ego lists.
__global__ __launch_bounds__(1024, 8) void k_hist(
        const int* __restrict__ srcp, const int* __restrict__ dstp,
        const unsigned* __restrict__ bitmap, const int* __restrict__ rep,
        unsigned* __restrict__ cnt, int* __restrict__ list,
        unsigned* __restrict__ partials) {
    __shared__ unsigned h[RWORDS];              // 50KB, four u8 counters/word
    const int r = blockIdx.x >> 7;              // node range 0..1
    const int b = blockIdx.x & (BPR - 1);       // edge slice 0..127
    uint4* h4 = reinterpret_cast<uint4*>(h);
    for (int i = threadIdx.x; i < RWORDS / 4; i += 1024) h4[i] = make_uint4(0u, 0u, 0u, 0u);
    __syncthreads();

    const int lo    = r * RSZ;
    const int ebase = b * SLICE;
    // balanced split of the 3125 int4s: r=0 -> [0,1562), r=1 -> [1562,3125)
    const int slo = (r * S4TOT) / NR;
    const int shi = ((r + 1) * S4TOT) / NR;
    const int4* dp = reinterpret_cast<const int4*>(dstp + ebase);
    const int4* sp = reinterpret_cast<const int4*>(srcp + ebase);

    for (int i = threadIdx.x; i < S4TOT; i += 1024) {
        const int4 d = dp[i];
        const int dv[4] = {d.x, d.y, d.z, d.w};
        const bool sc = (i >= slo) & (i < shi);
        int sv[4] = {0, 0, 0, 0};
        if (sc) {                                // coalesced src stream, half slice
            const int4 s = sp[i];
            sv[0] = s.x; sv[1] = s.y; sv[2] = s.z; sv[3] = s.w;
        }
        #pragma unroll
        for (int k = 0; k < 4; ++k) {
            // u8-packed histogram; per-block per-node mean 0.125, max ~8 << 255
            unsigned a = (unsigned)(dv[k] - lo);
            if (a < RSZ) atomicAdd(&h[a >> 2], 1u << (8 * (a & 3)));
            if (sc) {
                int dd = dv[k];
                if ((bitmap[(unsigned)dd >> 5] >> (dd & 31)) & 1u) {   // ~8% pass
                    int rr = rep[dd];
                    unsigned pos = atomicAdd(&cnt[rr], 1u);
                    if (pos < CAP) list[rr * CAP + pos] = sv[k];
                }
            }
        }
    }
    __syncthreads();

    uint4* outp = reinterpret_cast<uint4*>(partials + (size_t)blockIdx.x * RWORDS);
    for (int j = threadIdx.x; j < RWORDS / 4; j += 1024) outp[j] = h4[j];
}

// =============================== DISPATCH 4 ==================================
__global__ void k_red(const unsigned* __restrict__ partials,
                      float* __restrict__ dinv) {
    int j = blockIdx.x * blockDim.x + threadIdx.x;   // u32 word = 4 nodes
    if (j >= N_NODES / 4) return;
    int n0 = 4 * j;
    int r  = n0 / RSZ;
    int w  = (n0 - r * RSZ) >> 2;
    const unsigned* base = partials + (size_t)(r * BPR) * RWORDS + w;
    unsigned s02 = 0, s13 = 0;                   // SWAR: max 128*255 < 65536
    #pragma unroll 8
    for (int bb = 0; bb < BPR; ++bb) {
        unsigned v = base[(size_t)bb * RWORDS];
        s02 += v & 0x00FF00FFu;
        s13 += (v >> 8) & 0x00FF00FFu;
    }
    float4 o;
    o.x = rsqrtf((float)((s02 & 0xFFFFu) + 1u));   // +1 self-loop
    o.y = rsqrtf((float)((s13 & 0xFFFFu) + 1u));
    o.z = rsqrtf((float)((s02 >> 16) + 1u));
    o.w = rsqrtf((float)((s13 >> 16) + 1u));
    reinterpret_cast<float4*>(dinv)[j] = o;
}

// =============================== DISPATCH 5 ==================================
// 2048 blocks x 64 threads, 4 egos/wave (the measured-best round-1 shape).
__global__ __launch_bounds__(64) void k_mlp(
    const float* __restrict__ data1, const float* __restrict__ ego_time,
    const int* __restrict__ ego_idx,
    const float* __restrict__ F, const float* __restrict__ G,
    const float* __restrict__ C, const float* __restrict__ W2T,
    const float* __restrict__ b2,
    const int* __restrict__ rep, const unsigned* __restrict__ cnt,
    const int* __restrict__ list, const float* __restrict__ dinv,
    float* __restrict__ out) {
    __shared__ float mid_s[EPW][MID];
    const int lane = threadIdx.x;
    const int e    = lane >> 4;               // ego within wave 0..3
    const int sl   = lane & 15;               // slot within ego group
    const int i    = blockIdx.x * EPW + e;    // ego id (grid = N_EGO/EPW exact)
    const int node = ego_idx[i];
    const int r    = rep[node];
    int n = (int)cnt[r]; if (n > CAP) n = CAP;
    const float dvd = dinv[node];
    const int* lrow = list + (size_t)r * CAP;

    // s4_inner = sum_neighbors dinv[s]*x[s]  (+ dvd*x[node] self term)
    float px = 0.f, py = 0.f, pz = 0.f, pw = 0.f;
    for (int k = sl; k < n; k += 16) {
        int s = lrow[k];
        float w = dinv[s];
        float4 x = reinterpret_cast<const float4*>(data1)[s];
        px = fmaf(w, x.x, px); py = fmaf(w, x.y, py);
        pz = fmaf(w, x.z, pz); pw = fmaf(w, x.w, pw);
    }
    if (sl == 15) {
        float4 x = reinterpret_cast<const float4*>(data1)[node];
        px = fmaf(dvd, x.x, px); py = fmaf(dvd, x.y, py);
        pz = fmaf(dvd, x.z, pz); pw = fmaf(dvd, x.w, pw);
    }
    #pragma unroll
    for (int m = 1; m <= 8; m <<= 1) {        // butterfly within 16-lane group
        px += __shfl_xor(px, m);
        py += __shfl_xor(py, m);
        pz += __shfl_xor(pz, m);
        pw += __shfl_xor(pw, m);
    }
    const float sx = dvd * px, sy = dvd * py, sz = dvd * pz, sw = dvd * pw;
    const float t  = ego_time[i];

    // mid[m] for m = sl*4 .. sl*4+3
    const float4 f0 = reinterpret_cast<const float4*>(F)[0 * 16 + sl];
    const float4 f1 = reinterpret_cast<const float4*>(F)[1 * 16 + sl];
    const float4 f2 = reinterpret_cast<const float4*>(F)[2 * 16 + sl];
    const float4 f3 = reinterpret_cast<const float4*>(F)[3 * 16 + sl];
    const float4 g  = reinterpret_cast<const float4*>(G)[sl];
    const float4 c  = reinterpret_cast<const float4*>(C)[sl];
    float4 mid;
    mid.x = fmaxf(fmaf(sx, f0.x, fmaf(sy, f1.x, fmaf(sz, f2.x, fmaf(sw, f3.x, fmaf(t, g.x, c.x))))), 0.f);
    mid.y = fmaxf(fmaf(sx, f0.y, fmaf(sy, f1.y, fmaf(sz, f2.y, fmaf(sw, f3.y, fmaf(t, g.y, c.y))))), 0.f);
    mid.z = fmaxf(fmaf(sx, f0.z, fmaf(sy, f1.z, fmaf(sz, f2.z, fmaf(sw, f3.z, fmaf(t, g.z, c.z))))), 0.f);
    mid.w = fmaxf(fmaf(sx, f0.w, fmaf(sy, f1.w, fmaf(sz, f2.w, fmaf(sw, f3.w, fmaf(t, g.w, c.w))))), 0.f);
    reinterpret_cast<float4*>(mid_s[e])[sl] = mid;
    __syncthreads();

    // lin2: lane -> output o = sl of ego e
    float acc = b2[sl];
    const float4* m4 = reinterpret_cast<const float4*>(mid_s[e]);
    const float4* w4 = reinterpret_cast<const float4*>(W2T + sl * MID);
    #pragma unroll
    for (int q = 0; q < 16; ++q) {
        float4 mm = m4[q]; float4 ww = w4[q];
        acc = fmaf(mm.x, ww.x, acc); acc = fmaf(mm.y, ww.y, acc);
        acc = fmaf(mm.z, ww.z, acc); acc = fmaf(mm.w, ww.w, acc);
    }
    out[(size_t)i * OUT_D + sl] = 1.0f / (1.0f + expf(-acc));
}

// ===================== fallback: device-scope atomics (proven) ===============

__global__ void k_init_fb(unsigned* __restrict__ deg, int* __restrict__ rep,
                          unsigned* __restrict__ cnt, unsigned* __restrict__ bitmap) {
    int i = blockIdx.x * blockDim.x + threadIdx.x;
    if (i < N_NODES)  { deg[i] = 1u; rep[i] = INT_MAX; }
    if (i < N_EGO)    cnt[i] = 0u;
    if (i < BM_WORDS) bitmap[i] = 0u;
}

__global__ void k_rep_fb(const int* __restrict__ ego_idx, int* __restrict__ rep,
                         unsigned* __restrict__ bitmap) {
    int i = blockIdx.x * blockDim.x + threadIdx.x;
    if (i < N_EGO) {
        int node = ego_idx[i];
        atomicMin(&rep[node], i);
        atomicOr(&bitmap[node >> 5], 1u << (node & 31));
    }
}

__global__ __launch_bounds__(256) void k_edge_fb(
        const int* __restrict__ srcp, const int* __restrict__ dstp,
        unsigned* __restrict__ deg, const int* __restrict__ rep,
        const unsigned* __restrict__ bitmap,
        unsigned* __restrict__ cnt, int* __restrict__ list) {
    int t = blockIdx.x * blockDim.x + threadIdx.x;
    if (t * 4 >= N_EDGES) return;
    const int4 d4 = reinterpret_cast<const int4*>(dstp)[t];
    const int4 s4 = reinterpret_cast<const int4*>(srcp)[t];
    const int dv[4] = {d4.x, d4.y, d4.z, d4.w};
    const int sv[4] = {s4.x, s4.y, s4.z, s4.w};
    unsigned bm[4];
    #pragma unroll
    for (int k = 0; k < 4; ++k) {
        atomicAdd(&deg[dv[k]], 1u);
        bm[k] = bitmap[(unsigned)dv[k] >> 5];
    }
    #pragma unroll
    for (int k = 0; k < 4; ++k) {
        if ((bm[k] >> (dv[k] & 31)) & 1u) {
            int r = rep[dv[k]];
            unsigned pos = atomicAdd(&cnt[r], 1u);
            if (pos < CAP) list[r * CAP + pos] = sv[k];
        }
    }
}

__global__ void k_dinv_fb(const unsigned* __restrict__ deg, float* __restrict__ dinv) {
    int i = blockIdx.x * blockDim.x + threadIdx.x;
    if (i < N_NODES) dinv[i] = rsqrtf((float)deg[i]);
}

// ============================== launcher =====================================

extern "C" void kernel_launch(void* const* d_in, const int* in_sizes, int n_in,
                              void* d_out, int out_size, void* d_ws, size_t ws_size,
                              hipStream_t stream) {
    const float* data1    = (const float*)d_in[0];
    const int*   edge     = (const int*)d_in[1];   // [2, N_EDGES] int32
    const float* ego_time = (const float*)d_in[2];
    const int*   ego_idx  = (const int*)d_in[3];
    const float* convW    = (const float*)d_in[4];
    const float* convB    = (const float*)d_in[5];
    const float* w1       = (const float*)d_in[6];
    const float* b1       = (const float*)d_in[7];
    const float* w2       = (const float*)d_in[8];
    const float* b2       = (const float*)d_in[9];
    float* out = (float*)d_out;

    char* ws = (char*)d_ws;
    size_t off = 0;
    auto alloc = [&](size_t b) { size_t p = off; off += (b + 511) & ~(size_t)511; return p; };
    int*      rep    = (int*)     (ws + alloc((size_t)N_NODES * 4));
    unsigned* bitmap = (unsigned*)(ws + alloc((size_t)BM_WORDS * 4));
    unsigned* cnt    = (unsigned*)(ws + alloc((size_t)N_EGO * 4));
    float*    dinv   = (float*)   (ws + alloc((size_t)N_NODES * 4));
    float*    F      = (float*)   (ws + alloc((size_t)4 * MID * 4));
    float*    G      = (float*)   (ws + alloc((size_t)MID * 4));
    float*    C      = (float*)   (ws + alloc((size_t)MID * 4));
    float*    W2T    = (float*)   (ws + alloc((size_t)OUT_D * MID * 4));
    int*      list   = (int*)     (ws + alloc((size_t)N_EGO * CAP * 4));
    size_t tail = off;   // path-specific region
    unsigned* partials = (unsigned*)(ws + tail);            // NR*BPR*50KB = 12.8MB
    unsigned* deg      = (unsigned*)(ws + tail);            // 400KB (fallback)
    const size_t need_hist = tail + (size_t)NR * BPR * RWORDS * 4 + 512;
    const size_t need_fb   = tail + (size_t)N_NODES * 4 + 512;

    const int* srcp = edge;
    const int* dstp = edge + N_EDGES;

    if (ws_size >= need_hist) {
        hipLaunchKernelGGL(k_init3, dim3(3), dim3(1024), 0, stream,
                           convW, convB, w1, b1, w2, bitmap, cnt, F, G, C, W2T);
        hipLaunchKernelGGL(k_rep, dim3((N_EGO + 255) / 256), dim3(256), 0, stream,
                           ego_idx, rep, bitmap);
        hipLaunchKernelGGL(k_hist, dim3(NR * BPR), dim3(1024), 0, stream,
                           srcp, dstp, bitmap, rep, cnt, list, partials);
        hipLaunchKernelGGL(k_red, dim3((N_NODES / 4 + 255) / 256), dim3(256), 0, stream,
                           partials, dinv);
        hipLaunchKernelGGL(k_mlp, dim3(N_EGO / EPW), dim3(64), 0, stream,
                           data1, ego_time, ego_idx, F, G, C, W2T, b2,
                           rep, cnt, list, dinv, out);
    } else if (ws_size >= need_fb) {
        hipLaunchKernelGGL(k_init3, dim3(3), dim3(1024), 0, stream,
                           convW, convB, w1, b1, w2, bitmap, cnt, F, G, C, W2T);
        hipLaunchKernelGGL(k_init_fb, dim3((N_NODES + 255) / 256), dim3(256), 0, stream,
                           deg, rep, cnt, bitmap);
        hipLaunchKernelGGL(k_rep_fb, dim3((N_EGO + 255) / 256), dim3(256), 0, stream,
                           ego_idx, rep, bitmap);
        hipLaunchKernelGGL(k_edge_fb, dim3((N_EDGES / 4 + 255) / 256), dim3(256), 0, stream,
                           srcp, dstp, deg, rep, bitmap, cnt, list);
        hipLaunchKernelGGL(k_dinv_fb, dim3((N_NODES + 255) / 256), dim3(256), 0, stream,
                           deg, dinv);
        hipLaunchKernelGGL(k_mlp, dim3(N_EGO / EPW), dim3(64), 0, stream,
                           data1, ego_time, ego_idx, F, G, C, W2T, b2,
                           rep, cnt, list, dinv, out);
    }
}